// Round 8
// baseline (873.042 us; speedup 1.0000x reference)
//
#include <hip/hip_runtime.h>

// VQ-VAE quantization: N=32768, K=4096, D=256, fp32.
// Outputs (concat float32): z_q [N*D], idx [N] (as float), one_hot [N*K].
//
// Exact 3-way bf16 split (x=xh+xm+xl, exact for fp32's 24-bit mantissa);
// 6 MFMA products (hh,hm,mh,mm,hl,lh); rank by (||e||^2 - 2 z.e).
//
// Round-8: amortize A-fragment LDS reads. r7 was LDS-issue bound (12 ds_read_b128
// per 48 MFMA -> 1152 vs 466 cyc, MfmaUtil 46%). New split: 8 waves = 2 rowhalves
// x 4 codegroups (rt=2, u=4), kt tiled by 2 with acc held across the tile:
// 6 af reads per (ktile,dc) serve 96 MFMA -> LDS 576 < MFMA 931 cyc (MFMA-bound).

#define N_TOK 32768
#define K_CODE 4096
#define D_DIM 256
#define BM 64

typedef float f32x4 __attribute__((ext_vector_type(4)));
typedef short s16x8 __attribute__((ext_vector_type(8)));

// d_out tail scratch: e_frags ushort[3*K*D] = 6,291,456 B, then e2 float[K]
#define OUT_FLOATS 142639104u          // N*D + N + N*K
#define SCR_FLOATS 1576960u            // 3*K*D/2 + K
#define SCR_OFF    (OUT_FLOATS - SCR_FLOATS)
#define EFRAG_SHORTS (3u * K_CODE * D_DIM)
#define OH_SAFE_ROWS 32320             // rows >= this: one_hot overlaps scratch region

static __device__ __forceinline__ unsigned short f2bf(float f) {
    unsigned int u = __float_as_uint(f);
    u = (u + 0x7fffu + ((u >> 16) & 1u)) >> 16;
    return (unsigned short)u;
}
static __device__ __forceinline__ float bf2f(unsigned short b) {
    return __uint_as_float(((unsigned int)b) << 16);
}

// ---------------------------------------------------------------------------
// Prep: embed -> fragment-ordered bf16 h/m/l planes + e2.
// Frag layout (1KB): [ct_g(256)][dc(8)][c(3)][lane(64)][8 bf16];
// e[k][d]: ct_g=k>>4, n=k&15, dc=d>>5, quad=(d>>3)&3, j=d&7, lane=quad*16+n.
// ---------------------------------------------------------------------------
__global__ __launch_bounds__(256) void vq_prep(const float* __restrict__ embed,
                                               float* __restrict__ out) {
    __shared__ float part[8][33];
    unsigned short* escr = (unsigned short*)(out + SCR_OFF);
    float* e2g = out + SCR_OFF + (EFRAG_SHORTS / 2);

    const int t    = threadIdx.x;
    const int cl   = t >> 5;
    const int r32  = t & 31;
    const int dc   = r32 >> 2;
    const int quad = r32 & 3;
    const int k    = blockIdx.x * 8 + cl;

    const float* src = embed + (size_t)k * D_DIM + dc * 32 + quad * 8;
    float x[8];
    *(float4*)(x)     = *(const float4*)(src);
    *(float4*)(x + 4) = *(const float4*)(src + 4);

    s16x8 hv, mv, lv;
    float s2 = 0.0f;
#pragma unroll
    for (int j = 0; j < 8; ++j) {
        const float xx = x[j];
        s2 += xx * xx;
        const unsigned short bh = f2bf(xx);
        const float r1 = xx - bf2f(bh);
        const unsigned short bm = f2bf(r1);
        hv[j] = (short)bh; mv[j] = (short)bm; lv[j] = (short)f2bf(r1 - bf2f(bm));
    }

    const int ct_g = k >> 4;
    const int lane = quad * 16 + (k & 15);
    const size_t base = ((size_t)(ct_g * 8 + dc) * 3) * 512 + lane * 8;
    *(s16x8*)&escr[base]        = hv;
    *(s16x8*)&escr[base + 512]  = mv;
    *(s16x8*)&escr[base + 1024] = lv;

    part[cl][r32] = s2;
    __syncthreads();
    if (t < 8) {
        float s = 0.0f;
#pragma unroll
        for (int j = 0; j < 32; ++j) s += part[t][j];   // fixed order: deterministic
        e2g[blockIdx.x * 8 + t] = s;
    }
}

// ---- flattened step: fs in [0,128); ktile=fs>>4, dc=(fs>>1)&7, kt=fs&1 ----
static __device__ __forceinline__ void load_b(const unsigned short* __restrict__ escr,
                                              int fs, int cg, int lane,
                                              s16x8 (&buf)[4][3]) {
    const int ktstep = ((fs >> 4) << 1) + (fs & 1);
    const int dc     = (fs >> 1) & 7;
#pragma unroll
    for (int u = 0; u < 4; ++u) {
        const int ct_g = ktstep * 16 + cg * 4 + u;
        const unsigned short* p = &escr[((size_t)(ct_g * 8 + dc) * 3) * 512 + lane * 8];
#pragma unroll
        for (int c = 0; c < 3; ++c)
            buf[u][c] = *(const s16x8*)(p + c * 512);
    }
}

static __device__ __forceinline__ void proc_step(const short* As,
        const float* __restrict__ e2g, int fs, int rh, int cg, int lane, int n,
        s16x8 (&af)[2][3], s16x8 (&bfm)[4][3], f32x4 (&acc)[2][2][4],
        float (&bv)[8], int (&bidx)[8]) {
    const int kt = fs & 1;
    const int dc = (fs >> 1) & 7;

    if (kt == 0) {      // af serves both kt of this (ktile,dc)
#pragma unroll
        for (int rt = 0; rt < 2; ++rt) {
            const int rtl = rh * 2 + rt;
#pragma unroll
            for (int c = 0; c < 3; ++c)
                af[rt][c] = *(const s16x8*)&As[((c * 4 + rtl) * 8 + dc) * 512 + lane * 8];
        }
    }

#pragma unroll
    for (int rt = 0; rt < 2; ++rt)
#pragma unroll
        for (int u = 0; u < 4; ++u) {
            f32x4 a = acc[kt][rt][u];
            a = __builtin_amdgcn_mfma_f32_16x16x32_bf16(af[rt][0], bfm[u][0], a, 0, 0, 0);
            a = __builtin_amdgcn_mfma_f32_16x16x32_bf16(af[rt][0], bfm[u][1], a, 0, 0, 0);
            a = __builtin_amdgcn_mfma_f32_16x16x32_bf16(af[rt][1], bfm[u][0], a, 0, 0, 0);
            a = __builtin_amdgcn_mfma_f32_16x16x32_bf16(af[rt][1], bfm[u][1], a, 0, 0, 0);
            a = __builtin_amdgcn_mfma_f32_16x16x32_bf16(af[rt][0], bfm[u][2], a, 0, 0, 0);
            a = __builtin_amdgcn_mfma_f32_16x16x32_bf16(af[rt][2], bfm[u][0], a, 0, 0, 0);
            acc[kt][rt][u] = a;
        }

    if ((fs & 15) == 15) {   // end of ktile: merge both kt; codes ascend -> strict <
        const int ktile = fs >> 4;
#pragma unroll
        for (int kk = 0; kk < 2; ++kk)
#pragma unroll
            for (int u = 0; u < 4; ++u) {
                const int code = (ktile * 2 + kk) * 256 + cg * 64 + u * 16 + n;
                const float e2v = e2g[code];
#pragma unroll
                for (int rt = 0; rt < 2; ++rt)
#pragma unroll
                    for (int r = 0; r < 4; ++r) {
                        const float val = fmaf(-2.0f, acc[kk][rt][u][r], e2v);
                        const int slot = rt * 4 + r;
                        if (val < bv[slot]) { bv[slot] = val; bidx[slot] = code; }
                    }
            }
#pragma unroll
        for (int kk = 0; kk < 2; ++kk)
#pragma unroll
            for (int rt = 0; rt < 2; ++rt)
#pragma unroll
                for (int u = 0; u < 4; ++u)
                    acc[kk][rt][u] = (f32x4){0.f, 0.f, 0.f, 0.f};
    }
}

// ---------------------------------------------------------------------------
// Argmin + fused outputs: 512 thr = 8 waves = 2 rowhalves x 4 codegroups,
// 64 rows/block, grid 512 (1 block/CU, 2 rounds). LDS = A only (96KB).
// Flattened 128-step loop, ping-pong B prefetch, kt-tile=2 acc.
// Tail: idx + nontemporal z_q + one_hot (rows >= 32320 deferred).
// ---------------------------------------------------------------------------
__global__ __launch_bounds__(512, 2)
void vq_argmin_mfma(const float* __restrict__ z_e,
                    const float* __restrict__ embed,
                    float* __restrict__ out) {
    __shared__ __align__(16) short As[49152];   // [(c*4+rtl)*8+dc]*512 + ls*8
    __shared__ float redv[64][5];
    __shared__ int   redi[64][5];
    __shared__ int   bk_lds[64];

    const unsigned short* escr = (const unsigned short*)(out + SCR_OFF);
    const float* e2g = out + SCR_OFF + (EFRAG_SHORTS / 2);

    const int t    = threadIdx.x;
    const int w    = t >> 6;
    const int rh   = w >> 2;        // rowhalf 0..1 (32 rows each)
    const int cg   = w & 3;         // codegroup 0..3 (64 codes per kt-step)
    const int lane = t & 63;
    const int n    = lane & 15;
    const int quad = lane >> 4;
    const int row0 = blockIdx.x * BM;

    // ---- stage + convert A (once) ----
#pragma unroll
    for (int i = 0; i < 4; ++i) {
        const int run  = t + 512 * i;           // (row, dcs, qs): 64*8*4 = 2048
        const int qs   = run & 3;
        const int dcs  = (run >> 2) & 7;
        const int row  = run >> 5;
        const float* src = z_e + (size_t)(row0 + row) * D_DIM + dcs * 32 + qs * 8;
        float x[8];
        *(float4*)(x)     = *(const float4*)(src);
        *(float4*)(x + 4) = *(const float4*)(src + 4);
        s16x8 hv, mv, lv;
#pragma unroll
        for (int j = 0; j < 8; ++j) {
            const float xx = x[j];
            const unsigned short bh = f2bf(xx);
            const float r1 = xx - bf2f(bh);
            const unsigned short bm = f2bf(r1);
            hv[j] = (short)bh; mv[j] = (short)bm; lv[j] = (short)f2bf(r1 - bf2f(bm));
        }
        const int rtile = row >> 4;
        const int ls    = qs * 16 + (row & 15);
        *(s16x8*)&As[((0 * 4 + rtile) * 8 + dcs) * 512 + ls * 8] = hv;
        *(s16x8*)&As[((1 * 4 + rtile) * 8 + dcs) * 512 + ls * 8] = mv;
        *(s16x8*)&As[((2 * 4 + rtile) * 8 + dcs) * 512 + ls * 8] = lv;
    }
    __syncthreads();

    float bv[8];
    int   bidx[8];
#pragma unroll
    for (int s = 0; s < 8; ++s) { bv[s] = 3.0e38f; bidx[s] = 0; }

    f32x4 acc[2][2][4];     // [kt][rt][u]
#pragma unroll
    for (int kk = 0; kk < 2; ++kk)
#pragma unroll
        for (int rt = 0; rt < 2; ++rt)
#pragma unroll
            for (int u = 0; u < 4; ++u) acc[kk][rt][u] = (f32x4){0.f, 0.f, 0.f, 0.f};

    s16x8 af[2][3];
    s16x8 b0[4][3], b1[4][3];
    load_b(escr, 0, cg, lane, b0);

    // 128 steps; ping-pong prefetch distance 1 (b1's loads younger than b0's).
#pragma unroll 1
    for (int it = 0; it < 64; ++it) {
        const int s0 = it * 2, s1 = s0 + 1;
        load_b(escr, s1, cg, lane, b1);
        proc_step(As, e2g, s0, rh, cg, lane, n, af, b0, acc, bv, bidx);
        if (it < 63) load_b(escr, s1 + 1, cg, lane, b0);
        proc_step(As, e2g, s1, rh, cg, lane, n, af, b1, acc, bv, bidx);
    }

    // butterfly over 16 lanes (codes interleave mod 16 -> lex tie-break)
#pragma unroll
    for (int slot = 0; slot < 8; ++slot) {
#pragma unroll
        for (int mask = 1; mask < 16; mask <<= 1) {
            const float ov = __shfl_xor(bv[slot], mask);
            const int   oi = __shfl_xor(bidx[slot], mask);
            if (ov < bv[slot] || (ov == bv[slot] && oi < bidx[slot])) {
                bv[slot] = ov; bidx[slot] = oi;
            }
        }
    }
    if (n == 0) {
#pragma unroll
        for (int rt = 0; rt < 2; ++rt)
#pragma unroll
            for (int r = 0; r < 4; ++r) {
                const int row_local = (rh * 2 + rt) * 16 + quad * 4 + r;  // C/D: row=quad*4+reg
                redv[row_local][cg] = bv[rt * 4 + r];
                redi[row_local][cg] = bidx[rt * 4 + r];
            }
    }
    __syncthreads();
    if (t < 64) {
        float v = redv[t][0];
        int  bi = redi[t][0];
#pragma unroll
        for (int j = 1; j < 4; ++j) {
            const float v2 = redv[t][j];
            const int   i2 = redi[t][j];
            if (v2 < v || (v2 == v && i2 < bi)) { v = v2; bi = i2; }
        }
        bk_lds[t] = bi;
        out[(size_t)N_TOK * D_DIM + (size_t)(row0 + t)] = (float)bi;
    }
    __syncthreads();

    // ---- fused output tail (nontemporal: bypass L2, keep B scratch hot) ----
    float* zq = out;
    float* oh = out + (size_t)N_TOK * D_DIM + N_TOK;

#pragma unroll 1
    for (int rr = 0; rr < 8; ++rr) {            // z_q: wave w owns rows w*8..w*8+7
        const int rl  = w * 8 + rr;
        const int row = row0 + rl;
        const int bk  = bk_lds[rl];
        f32x4 v = *(const f32x4*)&embed[(size_t)bk * D_DIM + lane * 4];
        __builtin_nontemporal_store(v, (f32x4*)&zq[(size_t)row * D_DIM + lane * 4]);
    }
    if (row0 < OH_SAFE_ROWS) {                  // one_hot (scratch-overlap rows deferred)
#pragma unroll 1
        for (int rr = 0; rr < 8; ++rr) {
            const int rl  = w * 8 + rr;
            const int row = row0 + rl;
            const int bk  = bk_lds[rl];
            float* ohrow = &oh[(size_t)row * K_CODE];
#pragma unroll
            for (int g = 0; g < 16; ++g) {
                const int base = (g * 64 + lane) * 4;
                f32x4 u;
                u.x = (bk == base    ) ? 1.0f : 0.0f;
                u.y = (bk == base + 1) ? 1.0f : 0.0f;
                u.z = (bk == base + 2) ? 1.0f : 0.0f;
                u.w = (bk == base + 3) ? 1.0f : 0.0f;
                __builtin_nontemporal_store(u, (f32x4*)&ohrow[base]);
            }
        }
    }
}

// ---------------------------------------------------------------------------
// Cleanup: one_hot for rows 32320..32767 (region overlapped the scratch).
// ---------------------------------------------------------------------------
__launch_bounds__(256, 8)
__global__ void vq_oh_tail(float* __restrict__ out) {
    __shared__ int bks[16];
    const int t    = threadIdx.x;
    const int w    = t >> 6;
    const int lane = t & 63;
    const int row0 = OH_SAFE_ROWS + blockIdx.x * 16;

    const float* idxf = out + (size_t)N_TOK * D_DIM;
    float* oh = out + (size_t)N_TOK * D_DIM + N_TOK;

    if (t < 16) bks[t] = (int)idxf[row0 + t];
    __syncthreads();

#pragma unroll 1
    for (int rr = 0; rr < 4; ++rr) {
        const int r   = rr * 4 + w;
        const int row = row0 + r;
        const int bk  = bks[r];
        float* ohrow = &oh[(size_t)row * K_CODE];
#pragma unroll
        for (int g = 0; g < 16; ++g) {
            const int base = (g * 64 + lane) * 4;
            f32x4 u;
            u.x = (bk == base    ) ? 1.0f : 0.0f;
            u.y = (bk == base + 1) ? 1.0f : 0.0f;
            u.z = (bk == base + 2) ? 1.0f : 0.0f;
            u.w = (bk == base + 3) ? 1.0f : 0.0f;
            __builtin_nontemporal_store(u, (f32x4*)&ohrow[base]);
        }
    }
}

extern "C" void kernel_launch(void* const* d_in, const int* in_sizes, int n_in,
                              void* d_out, int out_size, void* d_ws, size_t ws_size,
                              hipStream_t stream) {
    const float* z_e   = (const float*)d_in[0];
    const float* embed = (const float*)d_in[1];
    float* out = (float*)d_out;

    hipLaunchKernelGGL(vq_prep,        dim3(K_CODE / 8), dim3(256), 0, stream, embed, out);
    hipLaunchKernelGGL(vq_argmin_mfma, dim3(N_TOK / BM), dim3(512), 0, stream, z_e, embed, out);
    hipLaunchKernelGGL(vq_oh_tail,     dim3((N_TOK - OH_SAFE_ROWS) / 16), dim3(256), 0, stream, out);
}